// Round 11
// baseline (104.727 us; speedup 1.0000x reference)
//
#include <hip/hip_runtime.h>

// Problem constants (match reference)
constexpr int   B_ = 8;
constexpr int   T_ = 100;
constexpr int   NPAIRS = B_ * T_;      // 800
constexpr int   N_ = 100000;
constexpr float MARGIN_ = 0.1f;
constexpr float THRESHOLD_ = 0.5f;
constexpr float BIG_ = 1000000000.0f;

// Main-kernel geometry.
// NBLK=2048, PER=49: 8 blocks/CU -> 32 waves/CU (FULL occupancy; R10's 1024/98
// gave 16 waves/CU and k_main appears latency-limited on its dependent
// sub->fma->sqrt->min chain).
constexpr int PER   = 49;              // splats per block
constexpr int NBLK  = 2048;            // k_main blocks (8/CU)
constexpr int NSLOT = 1024;            // padded pair slots (8 batches x 128)
constexpr int KCH   = 32;              // res-rows per reduction block
constexpr int NRED  = NBLK / KCH;      // 64 reduction blocks

// Workspace layout (bytes)
constexpr size_t RES_OFF  = 0;                                   // float[NBLK][NSLOT] = 8MB
constexpr size_t KEYS_OFF = RES_OFF + (size_t)NBLK * NSLOT * 4;  // uint[NSLOT] min-keys
constexpr size_t CNT_OFF  = KEYS_OFF + (size_t)NSLOT * 4;        // uint: finished-block counter

// fast hardware sqrt: single v_sqrt_f32
__device__ __forceinline__ float fsqrt(float x) { return __builtin_amdgcn_sqrtf(x); }

// Map float -> uint such that uint order == float order (handles negatives).
__device__ __forceinline__ unsigned fkey(float f) {
    unsigned u = __float_as_uint(f);
    return (u & 0x80000000u) ? ~u : (u | 0x80000000u);
}

// K1 (fused prep+pack+main): every block redundantly computes the 800 retrajs
// and 8 AABB boxes in LDS (~0.5 us of overlappable math), builds its PER splat
// records in LDS, then runs the interaction loop with WAVE-UNIFORM
// ds_read_b128 broadcasts. Each thread owns 4 slot-pairs as named scalars.
// Slot g: batch=g>>7, r=g&127 (r<100 -> real pair, else dummy).
// Waves 0,1 use eff vector 1 (even batches); waves 2,3 vector 2 (odd) --
// matches slot->batch = (j*256+tid)>>7 = 2j + (tid>>7).
// Block 0 also inits keys/cnt for k_red (visible via stream ordering).
// Results: plain coalesced stores to res[block][slot] (no contended atomics).
__global__ __launch_bounds__(256) void k_main(const float* __restrict__ outputs,
                                              const float* __restrict__ c2ws,
                                              const float* __restrict__ ss,
                                              const float* __restrict__ means,
                                              const float* __restrict__ scales,
                                              char* __restrict__ ws) {
    __shared__ float  re_s[NPAIRS * 3];
    __shared__ float  bounds_s[48];
    __shared__ float4 rec_s[PER * 3];
    int tid = threadIdx.x;

    if (blockIdx.x == 0) {  // init for k_red; k_red runs after all k_main blocks
        unsigned* keys = (unsigned*)(ws + KEYS_OFF);
        keys[tid]       = fkey(BIG_);
        keys[tid + 256] = fkey(BIG_);
        keys[tid + 512] = fkey(BIG_);
        keys[tid + 768] = fkey(BIG_);
        if (tid == 0) *(unsigned*)(ws + CNT_OFF) = 0;
    }

    // phase A: retrajs -> LDS (3.125 pairs/thread)
    for (int p = tid; p < NPAIRS; p += 256) {
        int b = p / T_;
        float s = ss[b];
        const float* o = outputs + p * 3;
        float o0 = o[0], o1 = o[1], o2 = o[2];
        const float* c = c2ws + b * 16;
#pragma unroll
        for (int e = 0; e < 3; e++) {
            re_s[p * 3 + e] =
                (o0 * c[e * 4 + 0] + o1 * c[e * 4 + 1] + o2 * c[e * 4 + 2]) * s + c[e * 4 + 3];
        }
    }
    __syncthreads();

    // phase B: per-(batch,axis) AABB bounds (24 lanes, serial over T)
    if (tid < 24) {
        int b = tid / 3, e = tid - b * 3;
        float mx = -3.4e38f, mn = 3.4e38f;
        for (int t = 0; t < T_; t++) {
            float v = re_s[(b * T_ + t) * 3 + e];
            mx = fmaxf(mx, v);
            mn = fminf(mn, v);
        }
        float thres = THRESHOLD_ * ss[0];  // reference uses scene_scales[0] for all b
        bounds_s[b * 3 + e]      = mn - thres;  // lvals
        bounds_s[24 + b * 3 + e] = mx + thres;  // uvals
    }
    __syncthreads();

    // phase C: per-thread slot-pairs from LDS + splat-record staging
    float4 q0, q1, q2, q3;
    {
        float4* qs[4] = {&q0, &q1, &q2, &q3};
#pragma unroll
        for (int j = 0; j < 4; j++) {
            int g = tid + j * 256;
            int bb = g >> 7, r = g & 127;
            float4 q = make_float4(0.f, 0.f, 0.f, 0.f);
            if (r < T_) {
                int p = bb * T_ + r;
                q = make_float4(re_s[p * 3 + 0], re_s[p * 3 + 1], re_s[p * 3 + 2], 0.f);
            }
            *qs[j] = q;
        }
    }
    if (tid < PER) {
        int n = blockIdx.x * PER + tid;  // grid is padded: 2048*49 > N
        float mx = 0.f, my = 0.f, mz = 0.f;
        float e0, e1, e2, e3, e4, e5, e6, e7;
        if (n < N_) {
            mx = means[(size_t)n * 3 + 0];
            my = means[(size_t)n * 3 + 1];
            mz = means[(size_t)n * 3 + 2];
            float msr = fmaxf(fmaxf(scales[(size_t)n * 3 + 0], scales[(size_t)n * 3 + 1]),
                              scales[(size_t)n * 3 + 2]) + MARGIN_;
            float e[8];
#pragma unroll
            for (int b = 0; b < 8; b++) {
                bool in = (mx >= bounds_s[b * 3 + 0]) & (mx <= bounds_s[24 + b * 3 + 0]) &
                          (my >= bounds_s[b * 3 + 1]) & (my <= bounds_s[24 + b * 3 + 1]) &
                          (mz >= bounds_s[b * 3 + 2]) & (mz <= bounds_s[24 + b * 3 + 2]);
                e[b] = in ? msr : -BIG_;
            }
            e0 = e[0]; e1 = e[1]; e2 = e[2]; e3 = e[3];
            e4 = e[4]; e5 = e[5]; e6 = e[6]; e7 = e[7];
        } else {
            e0 = e1 = e2 = e3 = e4 = e5 = e6 = e7 = -BIG_;
        }
        rec_s[tid * 3 + 0] = make_float4(mx, my, mz, 0.f);
        rec_s[tid * 3 + 1] = make_float4(e0, e2, e4, e6);
        rec_s[tid * 3 + 2] = make_float4(e1, e3, e5, e7);
    }
    __syncthreads();

    // wave-uniform eff selector: 1 for waves 0,1 (even batches), 2 for waves 2,3
    int effidx = 1 + ((__builtin_amdgcn_readfirstlane(tid) >> 7) & 1);

    float mn0 = BIG_, mn1 = BIG_, mn2 = BIG_, mn3 = BIG_;
#pragma unroll 2
    for (int i = 0; i < PER; i++) {
        float4 pos = rec_s[i * 3];
        float4 ef  = rec_s[i * 3 + effidx];
        float dx, dy, dz, d2;
        dx = q0.x - pos.x; dy = q0.y - pos.y; dz = q0.z - pos.z;
        d2 = fmaf(dz, dz, fmaf(dy, dy, dx * dx));
        mn0 = fminf(mn0, fsqrt(d2) - ef.x);
        dx = q1.x - pos.x; dy = q1.y - pos.y; dz = q1.z - pos.z;
        d2 = fmaf(dz, dz, fmaf(dy, dy, dx * dx));
        mn1 = fminf(mn1, fsqrt(d2) - ef.y);
        dx = q2.x - pos.x; dy = q2.y - pos.y; dz = q2.z - pos.z;
        d2 = fmaf(dz, dz, fmaf(dy, dy, dx * dx));
        mn2 = fminf(mn2, fsqrt(d2) - ef.z);
        dx = q3.x - pos.x; dy = q3.y - pos.y; dz = q3.z - pos.z;
        d2 = fmaf(dz, dz, fmaf(dy, dy, dx * dx));
        mn3 = fminf(mn3, fsqrt(d2) - ef.w);
    }

    float* res = (float*)(ws + RES_OFF) + (size_t)blockIdx.x * NSLOT;
    res[tid]       = mn0;
    res[tid + 256] = mn1;
    res[tid + 512] = mn2;
    res[tid + 768] = mn3;
}

// K2: parallel column-min over res. 64 blocks x 256 threads; block j reduces
// rows [j*32, j*32+32) for all 1024 slots (coalesced), one atomicMin per slot.
// Last block decodes keys, masks dummy slots, writes the scalar.
__global__ __launch_bounds__(256) void k_red(const char* __restrict__ wsc,
                                             char* __restrict__ ws,
                                             float* __restrict__ out) {
    __shared__ int   isLast;
    __shared__ float wsum[4];
    int tid = threadIdx.x;
    const float* res  = (const float*)(wsc + RES_OFF);
    unsigned*    keys = (unsigned*)(ws + KEYS_OFF);
    unsigned*    cnt  = (unsigned*)(ws + CNT_OFF);

    const float* row = res + (size_t)blockIdx.x * KCH * NSLOT;
    float mn0 = BIG_, mn1 = BIG_, mn2 = BIG_, mn3 = BIG_;
#pragma unroll 4
    for (int i = 0; i < KCH; i++) {
        mn0 = fminf(mn0, row[tid]);
        mn1 = fminf(mn1, row[tid + 256]);
        mn2 = fminf(mn2, row[tid + 512]);
        mn3 = fminf(mn3, row[tid + 768]);
        row += NSLOT;
    }
    atomicMin(&keys[tid],       fkey(mn0));
    atomicMin(&keys[tid + 256], fkey(mn1));
    atomicMin(&keys[tid + 512], fkey(mn2));
    atomicMin(&keys[tid + 768], fkey(mn3));

    __threadfence();  // release: make our atomicMin results visible
    if (tid == 0) isLast = (atomicAdd(cnt, 1u) == (unsigned)(NRED - 1));
    __syncthreads();
    if (isLast) {
        __threadfence();  // acquire: see all blocks' results
        float acc = 0.f;
        for (int s = tid; s < NSLOT; s += 256) {
            if ((s & 127) < T_) {
                unsigned k = __hip_atomic_load(&keys[s], __ATOMIC_RELAXED, __HIP_MEMORY_SCOPE_AGENT);
                unsigned u = (k & 0x80000000u) ? (k ^ 0x80000000u) : ~k;
                acc += fmaxf(0.f, -__uint_as_float(u));
            }
        }
#pragma unroll
        for (int off = 32; off; off >>= 1) acc += __shfl_down(acc, off, 64);
        if ((tid & 63) == 0) wsum[tid >> 6] = acc;
        __syncthreads();
        if (tid == 0)
            out[0] = (wsum[0] + wsum[1] + wsum[2] + wsum[3]) * (1.0f / (float)NPAIRS);
    }
}

extern "C" void kernel_launch(void* const* d_in, const int* in_sizes, int n_in,
                              void* d_out, int out_size, void* d_ws, size_t ws_size,
                              hipStream_t stream) {
    const float* outputs = (const float*)d_in[0];   // (B,T,3)
    const float* c2ws    = (const float*)d_in[1];   // (B,4,4)
    const float* ss      = (const float*)d_in[2];   // (B,)
    const float* means   = (const float*)d_in[3];   // (N,3)
    const float* scales  = (const float*)d_in[4];   // (N,3)
    float* out = (float*)d_out;
    char*  ws  = (char*)d_ws;

    hipLaunchKernelGGL(k_main, dim3(NBLK), dim3(256), 0, stream,
                       outputs, c2ws, ss, means, scales, ws);
    hipLaunchKernelGGL(k_red, dim3(NRED), dim3(256), 0, stream, (const char*)ws, ws, out);
}